// Round 6
// baseline (439.718 us; speedup 1.0000x reference)
//
#include <hip/hip_runtime.h>

#define D     4096   // row length
#define KKEEP 512    // entries to keep per row
#define TPB   512    // threads per block; TWO rows per block, 8 waves
#define NB    2048   // histogram bins (11-bit digits; round 2 uses low 1024 only)
#define BPT   (NB / TPB)             // 4 bins per thread in the scan
#define HA(d) ((d) + ((d) >> 2))     // stride-5 padded address: chunk base = 5*t
#define HWORDS (NB + NB / 4)         // 2560 words per histogram
#define NWAVE (TPB / 64)             // 8

// Monotonic float -> uint key: preserves total order of floats as unsigned ints.
__device__ __forceinline__ unsigned key_of(float f) {
    unsigned u = __float_as_uint(f);
    return (u & 0x80000000u) ? ~u : (u | 0x80000000u);
}
// Exact inverse of key_of.
__device__ __forceinline__ float val_of(unsigned k) {
    unsigned u = (k & 0x80000000u) ? (k ^ 0x80000000u) : ~k;
    return __uint_as_float(u);
}

// Two rows per block: the per-row FIXED select costs (2048-bin scans, shuffle
// chains [ds_bpermute = DS pipe], barriers) are shared: scans pack row A|B
// counts in 16-bit halves of one word (all counts <= 4096, no carry).
__global__ __launch_bounds__(TPB, 8)
void topk_keep_kernel(const float* __restrict__ x, float* __restrict__ out) {
    const int tid = threadIdx.x;
    const unsigned lane = tid & 63u, wid = (unsigned)tid >> 6;
    const long rowA = (long)blockIdx.x * 2;
    const float4* pxA = (const float4*)(x + rowA * D);
    const float4* pxB = pxA + (D / 4);
    float4* poA = (float4*)(out + rowA * D);
    float4* poB = poA + (D / 4);

    // ---- Coalesced loads: thread t owns float4 {t, t+512} of each row.
    // Element index of (j,t,c) = j*2048 + 4t + c -> (j,t,c) lex == index order.
    unsigned ka[8], kb[8];
    {
        float4 a0 = pxA[tid], a1 = pxA[tid + TPB];
        float4 b0 = pxB[tid], b1 = pxB[tid + TPB];
        ka[0]=key_of(a0.x); ka[1]=key_of(a0.y); ka[2]=key_of(a0.z); ka[3]=key_of(a0.w);
        ka[4]=key_of(a1.x); ka[5]=key_of(a1.y); ka[6]=key_of(a1.z); ka[7]=key_of(a1.w);
        kb[0]=key_of(b0.x); kb[1]=key_of(b0.y); kb[2]=key_of(b0.z); kb[3]=key_of(b0.w);
        kb[4]=key_of(b1.x); kb[5]=key_of(b1.y); kb[6]=key_of(b1.z); kb[7]=key_of(b1.w);
    }

    __shared__ unsigned hA[HWORDS], hB[HWORDS];
    __shared__ unsigned s_wtot[NWAVE];  // packed A|B<<16 wave chunk totals
    __shared__ unsigned s_sel[4];       // [digA, remA', digB, remB']
    __shared__ unsigned s_tA[NWAVE];    // tie: row A packed seg0|seg1 wave totals
    __shared__ unsigned s_tB[NWAVE];    // tie: row B

    // Zero once (incl. pad words 5t+4, never touched by atomics: HA covers
    // exactly words != 4 mod 5). Rounds 0/1 re-zero bins in the scan read-out.
    #pragma unroll
    for (int i = 0; i < HWORDS / TPB; ++i) {
        hA[tid + i * TPB] = 0;
        hB[tid + i * TPB] = 0;
    }
    __syncthreads();

    unsigned prefA = 0, prefB = 0;      // decided high bits of threshold keys
    unsigned remA = KKEEP, remB = KKEEP;

    // ---- 3-round radix select, fields [31:21], [20:10], [9:0] (MSB first)
    #pragma unroll
    for (int r = 0; r < 3; ++r) {
        const int shift = (r == 0) ? 21 : (r == 1) ? 10 : 0;
        const unsigned mask = (r == 2) ? 1023u : 2047u;

        if (r == 0) {
            #pragma unroll
            for (int j = 0; j < 8; ++j) {
                atomicAdd(&hA[HA(ka[j] >> 21)], 1u);
                atomicAdd(&hB[HA(kb[j] >> 21)], 1u);
            }
        } else {
            const int hs = (r == 1) ? 21 : 10;  // bits already decided
            #pragma unroll
            for (int j = 0; j < 8; ++j) {
                if ((ka[j] >> hs) == (prefA >> hs))
                    atomicAdd(&hA[HA((ka[j] >> shift) & mask)], 1u);
                if ((kb[j] >> hs) == (prefB >> hs))
                    atomicAdd(&hB[HA((kb[j] >> shift) & mask)], 1u);
            }
        }
        __syncthreads();

        // Packed scan: thread t owns bins [4t,4t+4) at words 5t..5t+3 of BOTH
        // hists (5 coprime 32 -> conflict-free). Fused re-zero for next round.
        unsigned c[BPT];
        unsigned ct = 0;
        {
            const int hb = tid * 5;
            #pragma unroll
            for (int i = 0; i < BPT; ++i) {
                unsigned cA = hA[hb + i], cB = hB[hb + i];
                c[i] = cA | (cB << 16);
                ct += c[i];
            }
            if (r < 2) {
                #pragma unroll
                for (int i = 0; i < BPT; ++i) { hA[hb + i] = 0; hB[hb + i] = 0; }
            }
        }
        unsigned s = ct;  // wave inclusive suffix scan (packed halves, no carry)
        #pragma unroll
        for (int off = 1; off < 64; off <<= 1) {
            unsigned t = __shfl_down(s, off, 64);
            if (lane + (unsigned)off < 64u) s += t;
        }
        if (lane == 0) s_wtot[wid] = s;
        __syncthreads();
        unsigned above = s - ct;
        #pragma unroll
        for (unsigned w = 0; w < NWAVE; ++w)
            if (w > wid) above += s_wtot[w];
        // walk my 4 bins top-down, both rows; one bin per row crosses `rem`
        unsigned runA = above & 0xffffu, runB = above >> 16;
        #pragma unroll
        for (int i = BPT - 1; i >= 0; --i) {
            unsigned cA = c[i] & 0xffffu, cB = c[i] >> 16;
            unsigned inclA = runA + cA;
            if (inclA >= remA && runA < remA) {
                s_sel[0] = (unsigned)(tid * BPT + i);
                s_sel[1] = remA - runA;
            }
            runA = inclA;
            unsigned inclB = runB + cB;
            if (inclB >= remB && runB < remB) {
                s_sel[2] = (unsigned)(tid * BPT + i);
                s_sel[3] = remB - runB;
            }
            runB = inclB;
        }
        __syncthreads();
        prefA |= s_sel[0] << shift; remA = s_sel[1];
        prefB |= s_sel[2] << shift; remB = s_sel[3];
    }

    const unsigned tkA = prefA, tkB = prefB;  // exact k-th largest keys

    // ---- Tie-break rank in element-index order, packed per row (2 segments).
    unsigned eA0 = 0, eA1 = 0, eB0 = 0, eB1 = 0;
    #pragma unroll
    for (int c2 = 0; c2 < 4; ++c2) {
        eA0 += (ka[c2] == tkA); eA1 += (ka[4 + c2] == tkA);
        eB0 += (kb[c2] == tkB); eB1 += (kb[4 + c2] == tkB);
    }
    unsigned pA = eA0 | (eA1 << 16), pB = eB0 | (eB1 << 16);
    unsigned iA = pA, iB = pB;  // wave inclusive scans (sums <= 4096 per half)
    #pragma unroll
    for (int off = 1; off < 64; off <<= 1) {
        unsigned t0 = __shfl_up(iA, off, 64);
        unsigned t1 = __shfl_up(iB, off, 64);
        if (lane >= (unsigned)off) { iA += t0; iB += t1; }
    }
    if (lane == 63) { s_tA[wid] = iA; s_tB[wid] = iB; }
    __syncthreads();
    unsigned xA = iA - pA, xB = iB - pB;  // exclusive within wave
    unsigned totA = 0, totB = 0;
    #pragma unroll
    for (unsigned w = 0; w < NWAVE; ++w) {
        unsigned a = s_tA[w], b = s_tB[w];
        if (w < wid) { xA += a; xB += b; }
        totA += a; totB += b;
    }
    unsigned rankA[2], rankB[2];  // global equal-rank of first equal per segment
    rankA[0] = xA & 0xffffu; rankA[1] = (totA & 0xffffu) + (xA >> 16);
    rankB[0] = xB & 0xffffu; rankB[1] = (totB & 0xffffu) + (xB >> 16);

    // ---- Emit (coalesced): keep keys > tkey, plus equals with rank < rem
    #pragma unroll
    for (int j = 0; j < 2; ++j) {
        float4 o;
        unsigned eqr = rankA[j];
        float* ofp = (float*)&o;
        #pragma unroll
        for (int c2 = 0; c2 < 4; ++c2) {
            unsigned kk = ka[4 * j + c2];
            bool keep;
            if (kk > tkA)       keep = true;
            else if (kk == tkA) { keep = (eqr < remA); ++eqr; }
            else                keep = false;
            ofp[c2] = keep ? val_of(kk) : 0.0f;
        }
        poA[tid + j * TPB] = o;
    }
    #pragma unroll
    for (int j = 0; j < 2; ++j) {
        float4 o;
        unsigned eqr = rankB[j];
        float* ofp = (float*)&o;
        #pragma unroll
        for (int c2 = 0; c2 < 4; ++c2) {
            unsigned kk = kb[4 * j + c2];
            bool keep;
            if (kk > tkB)       keep = true;
            else if (kk == tkB) { keep = (eqr < remB); ++eqr; }
            else                keep = false;
            ofp[c2] = keep ? val_of(kk) : 0.0f;
        }
        poB[tid + j * TPB] = o;
    }
}

extern "C" void kernel_launch(void* const* d_in, const int* in_sizes, int n_in,
                              void* d_out, int out_size, void* d_ws, size_t ws_size,
                              hipStream_t stream) {
    const float* x = (const float*)d_in[0];
    float* out = (float*)d_out;
    const int rows = in_sizes[0] / D;  // 4*4096 = 16384
    topk_keep_kernel<<<dim3(rows / 2), dim3(TPB), 0, stream>>>(x, out);
}

// Round 7
// 429.327 us; speedup vs baseline: 1.0242x; 1.0242x over previous
//
#include <hip/hip_runtime.h>

#define D     4096   // row length
#define KKEEP 512    // entries to keep per row
#define TPB   256    // threads per block (one block per row)
#define NSEG  4      // float4 segments per thread (D/4/TPB)
#define NB    2048   // histogram bins (11-bit digits; round 2 uses low 1024 only)
#define BPT   (NB / TPB)             // 8 bins per thread in the scan
#define HA(d) ((d) + ((d) >> 3))     // padded hist address: chunk base = 9*tid
#define HWORDS (NB + NB / 8)         // 2304 words

// Monotonic float -> uint key, 3 VALU ops (ashr, or, xor).
// msb set (negative): mask=0xffffffff -> ~u. msb clear: mask=0x80000000 -> u|msb.
__device__ __forceinline__ unsigned key_of(float f) {
    unsigned u = __float_as_uint(f);
    return u ^ ((unsigned)((int)u >> 31) | 0x80000000u);
}

// VALU-bound kernel (model: ~500 inst/thread ~ 4000 cyc/block > 3200-cyc memory
// floor). This version cuts ~180 inst/thread: tie fast path + stored floats.
__global__ __launch_bounds__(TPB, 6)
void topk_keep_kernel(const float* __restrict__ x, float* __restrict__ out) {
    const int tid = threadIdx.x;
    const unsigned lane = tid & 63u, wid = (unsigned)tid >> 6;
    const float4* px = (const float4*)(x + (long)blockIdx.x * D);
    float4*       po = (float4*)(out + (long)blockIdx.x * D);

    // ---- Coalesced load: thread t owns float4 indices {t + 256*j}.
    // Element index of (j, t, c) = j*1024 + 4t + c  → (j,t,c) lex == index order.
    // Keep BOTH the float and its key live: emit then needs no val_of (2 ops/elem).
    unsigned k[NSEG * 4];
    float    fv[NSEG * 4];
    {
        float4 f0 = px[tid], f1 = px[tid + TPB], f2 = px[tid + 2 * TPB], f3 = px[tid + 3 * TPB];
        fv[ 0]=f0.x; fv[ 1]=f0.y; fv[ 2]=f0.z; fv[ 3]=f0.w;
        fv[ 4]=f1.x; fv[ 5]=f1.y; fv[ 6]=f1.z; fv[ 7]=f1.w;
        fv[ 8]=f2.x; fv[ 9]=f2.y; fv[10]=f2.z; fv[11]=f2.w;
        fv[12]=f3.x; fv[13]=f3.y; fv[14]=f3.z; fv[15]=f3.w;
        #pragma unroll
        for (int j = 0; j < 16; ++j) k[j] = key_of(fv[j]);
    }

    __shared__ unsigned hist[HWORDS];
    __shared__ unsigned s_wtot[4];    // per-wave chunk totals (select scan)
    __shared__ unsigned s_sel[3];     // [selected digit, new remaining, bin count]
    __shared__ unsigned s_w01[4];     // tie slow path: packed seg0|seg1 wave totals
    __shared__ unsigned s_w23[4];     // tie slow path: packed seg2|seg3 wave totals

    // Zero once (incl. pad words 9t+8, never touched by atomics). Rounds 0/1
    // re-zero their bins in the scan read-out (fused, conflict-free 9-stride).
    #pragma unroll
    for (int i = 0; i < 9; ++i) hist[tid + i * TPB] = 0;
    __syncthreads();

    unsigned prefix = 0;   // decided high bits of threshold key (in place)
    unsigned rem = KKEEP;  // rank still to satisfy within current prefix subset
    unsigned eqn = 0;      // count of keys == final threshold (round 2 bin count)

    // ---- 3-round radix select, fields [31:21], [20:10], [9:0] (MSB first)
    #pragma unroll
    for (int r = 0; r < 3; ++r) {
        const int shift = (r == 0) ? 21 : (r == 1) ? 10 : 0;
        const unsigned mask = (r == 2) ? 1023u : 2047u;

        if (r == 0) {
            #pragma unroll
            for (int j = 0; j < 16; ++j)
                atomicAdd(&hist[HA(k[j] >> 21)], 1u);
        } else {
            const int hs = (r == 1) ? 21 : 10;  // bits already decided
            #pragma unroll
            for (int j = 0; j < 16; ++j)
                if ((k[j] >> hs) == (prefix >> hs))
                    atomicAdd(&hist[HA((k[j] >> shift) & mask)], 1u);
        }
        __syncthreads();

        // All-thread suffix scan: thread t owns bins [8t, 8t+8) at words 9t..9t+7
        // (9 coprime to 32 -> conflict-free). Fused re-zero for the next round.
        unsigned c[BPT];
        unsigned ct = 0;
        {
            const int hb = tid * 9;
            #pragma unroll
            for (int i = 0; i < BPT; ++i) { c[i] = hist[hb + i]; ct += c[i]; }
            if (r < 2) {
                #pragma unroll
                for (int i = 0; i < BPT; ++i) hist[hb + i] = 0;
            }
        }
        unsigned s = ct;  // wave inclusive suffix scan of chunk totals
        #pragma unroll
        for (int off = 1; off < 64; off <<= 1) {
            unsigned t = __shfl_down(s, off, 64);
            if (lane + (unsigned)off < 64u) s += t;
        }
        if (lane == 0) s_wtot[wid] = s;
        __syncthreads();
        unsigned above = s - ct;
        #pragma unroll
        for (unsigned w = 0; w < 4; ++w)
            if (w > wid) above += s_wtot[w];
        unsigned run = above;  // walk my 8 bins top-down; one bin crosses `rem`
        #pragma unroll
        for (int i = BPT - 1; i >= 0; --i) {
            unsigned incl = run + c[i];
            if (incl >= rem && run < rem) {
                s_sel[0] = (unsigned)(tid * BPT + i);
                s_sel[1] = rem - run;
                s_sel[2] = c[i];
            }
            run = incl;
        }
        __syncthreads();
        prefix |= s_sel[0] << shift;
        rem = s_sel[1];
        eqn = s_sel[2];
    }

    const unsigned tkey = prefix;  // exact k-th largest key; rem = # equals to keep

    // ---- Tie fast path: rem == eqn means ALL threshold-equals are kept, so
    // keep == (key >= tkey) with no ranking. For continuous random data the
    // threshold value is unique (eqn=1=rem) in ~all rows. Block-uniform branch.
    if (rem == eqn) {
        #pragma unroll
        for (int j = 0; j < NSEG; ++j) {
            float4 o;
            float* ofp = (float*)&o;
            #pragma unroll
            for (int c = 0; c < 4; ++c) {
                const int idx = 4 * j + c;
                ofp[c] = (k[idx] >= tkey) ? fv[idx] : 0.0f;  // 2 ops/elem
            }
            po[tid + j * TPB] = o;
        }
        return;
    }

    // ---- Slow path (rare): tie-break rank in element-index order.
    // Packed per-segment equal counts: p01 = e0 | e1<<16, p23 = e2 | e3<<16.
    unsigned e[NSEG];
    #pragma unroll
    for (int j = 0; j < NSEG; ++j) {
        unsigned c0 = (k[4*j+0] == tkey), c1 = (k[4*j+1] == tkey);
        unsigned c2 = (k[4*j+2] == tkey), c3 = (k[4*j+3] == tkey);
        e[j] = c0 + c1 + c2 + c3;
    }
    unsigned p01 = e[0] | (e[1] << 16);
    unsigned p23 = e[2] | (e[3] << 16);
    unsigned i01 = p01, i23 = p23;  // wave inclusive scans (sums ≤1024 per half)
    #pragma unroll
    for (int off = 1; off < 64; off <<= 1) {
        unsigned t0 = __shfl_up(i01, off, 64);
        unsigned t1 = __shfl_up(i23, off, 64);
        if (lane >= (unsigned)off) { i01 += t0; i23 += t1; }
    }
    if (lane == 63) { s_w01[wid] = i01; s_w23[wid] = i23; }
    __syncthreads();
    unsigned x01 = i01 - p01, x23 = i23 - p23;  // exclusive within wave
    #pragma unroll
    for (unsigned w = 0; w < 4; ++w)
        if (w < wid) { x01 += s_w01[w]; x23 += s_w23[w]; }
    const unsigned tot01 = s_w01[0] + s_w01[1] + s_w01[2] + s_w01[3];
    const unsigned tot23 = s_w23[0] + s_w23[1] + s_w23[2] + s_w23[3];
    const unsigned total0 = tot01 & 0xffffu, total1 = tot01 >> 16;
    const unsigned total2 = tot23 & 0xffffu;
    unsigned rank[NSEG];  // global equal-rank of my first equal in each segment
    rank[0] = (x01 & 0xffffu);
    rank[1] = total0 + (x01 >> 16);
    rank[2] = total0 + total1 + (x23 & 0xffffu);
    rank[3] = total0 + total1 + total2 + (x23 >> 16);

    // ---- Emit (coalesced): keep keys > tkey, plus equals with rank < rem
    #pragma unroll
    for (int j = 0; j < NSEG; ++j) {
        float4 o;
        unsigned eqr = rank[j];
        float* ofp = (float*)&o;
        #pragma unroll
        for (int c = 0; c < 4; ++c) {
            const int idx = 4 * j + c;
            unsigned kk = k[idx];
            bool keep;
            if (kk > tkey)       keep = true;
            else if (kk == tkey) { keep = (eqr < rem); ++eqr; }
            else                 keep = false;
            ofp[c] = keep ? fv[idx] : 0.0f;
        }
        po[tid + j * TPB] = o;
    }
}

extern "C" void kernel_launch(void* const* d_in, const int* in_sizes, int n_in,
                              void* d_out, int out_size, void* d_ws, size_t ws_size,
                              hipStream_t stream) {
    const float* x = (const float*)d_in[0];
    float* out = (float*)d_out;
    const int rows = in_sizes[0] / D;  // 4*4096 = 16384
    topk_keep_kernel<<<dim3(rows), dim3(TPB), 0, stream>>>(x, out);
}